// Round 2
// baseline (5989.498 us; speedup 1.0000x reference)
//
#include <hip/hip_runtime.h>
#include <math.h>

#define B_ 16
#define T_ 4096
#define D_ 512
#define T1_ 4097

#define TT 32          // t-rows per block
#define LT 8           // t-rows per thread
#define NTHR 512
#define ICB_N 256      // 512 / IC, IC = 2

#define SMOOTH_FACTOR 1.0
#define NOISE_THRESHOLD 0.0
#define TAIL_THRESHOLD 0.45

// ---- workspace layout (bytes) ----
#define WT_OFF   ((size_t)0)         // f64 wt2 stream [icb][ii][k][o]: 3*512*512*8 = 6291456
#define PART_OFF ((size_t)6291456)   // f64 partial[b][t][2]: 1048576
#define A64_OFF  ((size_t)7340032)   // f64 alpha[b][T1]: 524416
#define FT_OFF   ((size_t)7864448)   // i32 fire_t[b][T1]: 262208
#define FF_OFF   ((size_t)8126656)   // f64 fire_frac[b][T1]: 524416
#define LEN_OFF  ((size_t)8651072)   // i32 batch_len[b]: 64

// ============ K0: conv_w [o][i][k] f32 -> wt2 stream [icb][ii][k][o] f64 ============
__global__ void k_wt(const float* __restrict__ cw, double* __restrict__ wt2) {
    int idx = blockIdx.x * 256 + threadIdx.x;
    if (idx >= 3 * D_ * D_) return;
    int icb = idx / 3072;
    int r   = idx - icb * 3072;
    int ii  = r / 1536;
    int r2  = r - ii * 1536;
    int k   = r2 >> 9;
    int o   = r2 & 511;
    int i   = icb * 2 + ii;
    wt2[idx] = (double)cw[(o * D_ + i) * 3 + k];
}

// ============ K1: f64 conv + fused relu-dot partial reduction ============
// grid (T_/TT, B_), 512 threads. og = tid&127 (o = og+128j), tg = wave>>1, 8 t each.
// W double-buffered in LDS (one barrier/chunk); h via wave-uniform scalar loads.
__global__ __launch_bounds__(NTHR, 4)
void k_conv(const float* __restrict__ h, const double* __restrict__ wt2,
            const float* __restrict__ cb, const float* __restrict__ ow,
            double* __restrict__ part) {
    __shared__ double wls[2][3072];   // 49152 B -> 2 blocks/CU

    const int tid  = threadIdx.x;
    const int b    = blockIdx.y;
    const int t0   = blockIdx.x * TT;
    const int og   = tid & 127;
    const int wave = __builtin_amdgcn_readfirstlane(tid >> 6);
    const int tg   = wave >> 1;
    const int tbase = t0 + tg * LT;

    // uniform h row pointers (SGPR) for rows tbase-1 .. tbase+LT
    const float* hb = h + (size_t)b * T_ * D_;
    const float* hrow[LT + 2];
    bool hvalid[LT + 2];
    #pragma unroll
    for (int rr = 0; rr < LT + 2; ++rr) {
        int t = tbase - 1 + rr;
        hvalid[rr] = (t >= 0 && t < T_);
        hrow[rr] = hb + (size_t)(hvalid[rr] ? t : 0) * D_;
    }

    double acc[LT][4];
    #pragma unroll
    for (int a = 0; a < LT; ++a)
        #pragma unroll
        for (int j = 0; j < 4; ++j) acc[a][j] = 0.0;

    // register prefetch of the W chunk stream (3 x double2 per thread)
    double2 wreg[3];
    {
        const double* src = wt2;   // chunk 0
        #pragma unroll
        for (int s = 0; s < 3; ++s)
            wreg[s] = *(const double2*)(src + (size_t)(tid + s * NTHR) * 2);
    }

    for (int icb = 0; icb < ICB_N; ++icb) {
        const int cur = icb & 1;
        // (1) commit prefetched chunk icb to LDS
        #pragma unroll
        for (int s = 0; s < 3; ++s)
            *(double2*)(&wls[cur][(tid + s * NTHR) * 2]) = wreg[s];
        // (2) barrier: chunk icb visible; prior reads of this buffer long done
        __syncthreads();
        // (3) issue prefetch of chunk icb+1 (drains at NEXT barrier -> hidden)
        if (icb + 1 < ICB_N) {
            const double* src = wt2 + (size_t)(icb + 1) * 3072;
            #pragma unroll
            for (int s = 0; s < 3; ++s)
                wreg[s] = *(const double2*)(src + (size_t)(tid + s * NTHR) * 2);
        }
        // (4) compute on chunk icb
        const int i0 = icb * 2;
        #pragma unroll
        for (int ii = 0; ii < 2; ++ii) {
            double hd[LT + 2];
            #pragma unroll
            for (int rr = 0; rr < LT + 2; ++rr)
                hd[rr] = (double)(hvalid[rr] ? hrow[rr][i0 + ii] : 0.0f);
            #pragma unroll
            for (int k = 0; k < 3; ++k) {
                #pragma unroll
                for (int j = 0; j < 4; ++j) {
                    double wv = wls[cur][ii * 1536 + k * 512 + og + (j << 7)];
                    #pragma unroll
                    for (int lt = 0; lt < LT; ++lt)
                        acc[lt][j] = fma(hd[lt + k], wv, acc[lt][j]);
                }
            }
        }
        __syncthreads();
    }

    // epilogue: p(t) = sum_o out_w[o]*relu(z+conv_b[o]); 64-lane reduce
    float cbf[4], owf[4];
    #pragma unroll
    for (int j = 0; j < 4; ++j) {
        cbf[j] = cb[og + (j << 7)];
        owf[j] = ow[og + (j << 7)];
    }
    const int lane = tid & 63;
    const int half = (tid >> 6) & 1;
    #pragma unroll
    for (int lt = 0; lt < LT; ++lt) {
        double p = 0.0;
        #pragma unroll
        for (int j = 0; j < 4; ++j) {
            double z = acc[lt][j] + (double)cbf[j];
            z = z > 0.0 ? z : 0.0;
            p = fma((double)owf[j], z, p);
        }
        #pragma unroll
        for (int off = 32; off > 0; off >>= 1) p += __shfl_xor(p, off);
        if (lane == 0)
            part[((size_t)b * T_ + tbase + lt) * 2 + half] = p;
    }
}

// ============ K2: per-batch alpha finish + wave prefix-scan + fire records ============
__global__ void k_scan(const double* __restrict__ part, const float* __restrict__ mask,
                       const float* __restrict__ outb,
                       float* __restrict__ out_tok, float* __restrict__ out_alpha,
                       double* __restrict__ a64, int* __restrict__ fire_t,
                       double* __restrict__ fire_frac, int* __restrict__ blen) {
    const int b = blockIdx.x;
    const int lane = threadIdx.x;
    const double ob = (double)outb[0];
    double carry = 0.0;
    int nf = 0;

    for (int c = 0; c < 65; ++c) {
        int t = c * 64 + lane;
        double a = 0.0;
        if (t < T_) {
            double o = part[((size_t)b * T_ + t) * 2] +
                       part[((size_t)b * T_ + t) * 2 + 1] + ob;
            double s = 1.0 / (1.0 + exp(-o));
            double ap = s * SMOOTH_FACTOR - NOISE_THRESHOLD;
            if (ap < 0.0) ap = 0.0;
            double mk = (double)mask[b * T_ + t];
            double mprev = (t == 0) ? 1.0 : (double)mask[b * T_ + t - 1];
            a = ap * mk + TAIL_THRESHOLD * (mprev - mk);
        } else if (t == T_) {
            double mprev = (double)mask[b * T_ + T_ - 1];
            a = TAIL_THRESHOLD * mprev;
        }
        if (t <= T_) {
            out_alpha[(size_t)b * T1_ + t] = (float)a;
            a64[(size_t)b * T1_ + t] = a;
        }
        double x = a;
        #pragma unroll
        for (int off = 1; off < 64; off <<= 1) {
            double y = __shfl_up(x, off);
            if (lane >= off) x += y;
        }
        double ps = carry + x;
        double ps_prev = __shfl_up(ps, 1);
        if (lane == 0) ps_prev = carry;
        double psf = floor(ps), ppsf = floor(ps_prev);
        bool fire = (t <= T_) && (psf > ppsf);
        unsigned long long m = __ballot(fire);
        if (fire) {
            int k = nf + (int)__popcll(m & ((1ull << lane) - 1ull));
            fire_t[(size_t)b * T1_ + k] = t;
            fire_frac[(size_t)b * T1_ + k] = ps - psf;
        }
        nf += (int)__popcll(m);
        carry = __shfl(ps, 63);
    }
    if (lane == 0) {
        blen[b] = nf;
        out_tok[b] = (float)floor(carry);
    }
}

// ============ K3: frame construction (f64 accumulate) ============
__global__ void k_frames(const float* __restrict__ h, const double* __restrict__ a64,
                         const int* __restrict__ fire_t, const double* __restrict__ fire_frac,
                         const int* __restrict__ blen, float* __restrict__ out, int K) {
    const int k = blockIdx.x;
    const int b = blockIdx.y;
    const int tid = threadIdx.x;
    double ax = 0.0, ay = 0.0, az = 0.0, aw = 0.0;
    const int len = blen[b];
    if (k < len) {
        const int t1 = fire_t[(size_t)b * T1_ + k];
        const int t0 = (k > 0) ? fire_t[(size_t)b * T1_ + k - 1] : -1;
        const double f1 = fire_frac[(size_t)b * T1_ + k];
        const double f0 = (k > 0) ? fire_frac[(size_t)b * T1_ + k - 1] : 0.0;
        if (t0 >= 0 && t0 < T_) {
            float4 hv = *(const float4*)(h + ((size_t)b * T_ + t0) * D_ + (tid << 2));
            ax = fma(f0, (double)hv.x, ax); ay = fma(f0, (double)hv.y, ay);
            az = fma(f0, (double)hv.z, az); aw = fma(f0, (double)hv.w, aw);
        }
        for (int t = t0 + 1; t <= t1; ++t) {
            if (t >= T_) break;
            double c = a64[(size_t)b * T1_ + t] - ((t == t1) ? f1 : 0.0);
            float4 hv = *(const float4*)(h + ((size_t)b * T_ + t) * D_ + (tid << 2));
            ax = fma(c, (double)hv.x, ax); ay = fma(c, (double)hv.y, ay);
            az = fma(c, (double)hv.z, az); aw = fma(c, (double)hv.w, aw);
        }
    }
    float4 o = make_float4((float)ax, (float)ay, (float)az, (float)aw);
    *(float4*)(out + ((size_t)b * K + k) * D_ + (tid << 2)) = o;
}

// ============ host ============
extern "C" void kernel_launch(void* const* d_in, const int* in_sizes, int n_in,
                              void* d_out, int out_size, void* d_ws, size_t ws_size,
                              hipStream_t stream) {
    const float* h    = (const float*)d_in[0];
    const float* mask = (const float*)d_in[1];
    const float* cw   = (const float*)d_in[2];
    const float* cb   = (const float*)d_in[3];
    const float* ow   = (const float*)d_in[4];
    const float* ob   = (const float*)d_in[5];

    char* ws = (char*)d_ws;
    double* wt2       = (double*)(ws + WT_OFF);
    double* part      = (double*)(ws + PART_OFF);
    double* a64       = (double*)(ws + A64_OFF);
    int*    fire_t    = (int*)(ws + FT_OFF);
    double* fire_frac = (double*)(ws + FF_OFF);
    int*    blen      = (int*)(ws + LEN_OFF);

    long long K = ((long long)out_size - B_ - (long long)B_ * T1_) / ((long long)B_ * D_);
    if (K < 1) K = 1;
    float* out_ac    = (float*)d_out;
    float* out_tok   = out_ac + (size_t)B_ * K * D_;
    float* out_alpha = out_tok + B_;

    k_wt<<<dim3((3 * D_ * D_ + 255) / 256), dim3(256), 0, stream>>>(cw, wt2);
    k_conv<<<dim3(T_ / TT, B_), dim3(NTHR), 0, stream>>>(h, wt2, cb, ow, part);
    k_scan<<<dim3(B_), dim3(64), 0, stream>>>(part, mask, ob, out_tok, out_alpha,
                                              a64, fire_t, fire_frac, blen);
    k_frames<<<dim3((unsigned)K, B_), dim3(128), 0, stream>>>(h, a64, fire_t, fire_frac,
                                                              blen, out_ac, (int)K);
}

// Round 3
// 1690.948 us; speedup vs baseline: 3.5421x; 3.5421x over previous
//
#include <hip/hip_runtime.h>
#include <math.h>

#define B_ 16
#define T_ 4096
#define D_ 512
#define T1_ 4097

#define NTHR 512       // 8 waves
#define HPAD 516       // padded LDS row stride (f32)

#define SMOOTH_FACTOR 1.0
#define NOISE_THRESHOLD 0.0
#define TAIL_THRESHOLD 0.45

typedef double d4 __attribute__((ext_vector_type(4)));

// ---- workspace layout (bytes) ----
#define WTF_OFF  ((size_t)0)         // f32 W [k][i][o]: 3*512*512*4 = 3145728
#define PART_OFF ((size_t)3145728)   // f64 partial[b][t][8]: 16*4096*8*8 = 4194304
#define A64_OFF  ((size_t)7340032)   // f64 alpha[b][T1]: 524416
#define FT_OFF   ((size_t)7864448)   // i32 fire_t[b][T1]: 262208
#define FF_OFF   ((size_t)8126656)   // f64 fire_frac[b][T1]: 524416
#define LEN_OFF  ((size_t)8651072)   // i32 batch_len[b]: 64

// ============ K0: conv_w [o][i][k] f32 -> wtf [k][i][o] f32 ============
__global__ void k_wt(const float* __restrict__ cw, float* __restrict__ wtf) {
    int idx = blockIdx.x * 256 + threadIdx.x;
    if (idx >= 3 * D_ * D_) return;
    int o = idx & 511;
    int r = idx >> 9;          // k*512 + i
    int i = r & 511;
    int k = r >> 9;
    wtf[idx] = cw[(o * D_ + i) * 3 + k];
}

// ============ K1: f64 MFMA conv + fused relu-dot partials ============
// grid (T_/16, B_), 512 threads (8 waves). Block covers 16 t-rows; wave w owns
// o in [w*64, w*64+64) as 4 MFMA o-tiles. K = 3 taps x 512 i, stepped 4 i at a time.
__global__ __launch_bounds__(NTHR)
void k_conv(const float* __restrict__ h, const float* __restrict__ wtf,
            const float* __restrict__ cb, const float* __restrict__ ow,
            double* __restrict__ part) {
    __shared__ float hs[18 * HPAD];   // rows t0-1 .. t0+16, 37152 B

    const int tid  = threadIdx.x;
    const int b    = blockIdx.y;
    const int t0   = blockIdx.x * 16;
    const int lane = tid & 63;
    const int w    = tid >> 6;        // wave 0..7
    const int rw   = lane & 15;       // A row (t_local) / B-D col (o within tile)
    const int kg   = lane >> 4;       // k-slot within fragment (i offset 0..3)

    // ---- stage h tile (f32) into LDS, zero-padded halo; ONE barrier ----
    const float* hb = h + (size_t)b * T_ * D_;
    for (int idx = tid; idx < 18 * 128; idx += NTHR) {
        int r  = idx >> 7;
        int c4 = idx & 127;
        int t  = t0 - 1 + r;
        float4 v = make_float4(0.f, 0.f, 0.f, 0.f);
        if (t >= 0 && t < T_)
            v = *(const float4*)(hb + (size_t)t * D_ + (c4 << 2));
        *(float4*)(&hs[r * HPAD + (c4 << 2)]) = v;
    }
    __syncthreads();

    d4 acc[4];
    #pragma unroll
    for (int ot = 0; ot < 4; ++ot) acc[ot] = (d4){0.0, 0.0, 0.0, 0.0};

    // B-fragment global base: wtf[(tap*512 + i)*512 + w*64 + ot*16 + rw]
    const float* wbase = wtf + (size_t)(w * 64) + rw;

    #define LOADW(I0, DST)                                                      \
        _Pragma("unroll")                                                       \
        for (int tap = 0; tap < 3; ++tap)                                       \
            _Pragma("unroll")                                                   \
            for (int ot = 0; ot < 4; ++ot)                                      \
                DST[tap * 4 + ot] =                                             \
                    wbase[((size_t)(((tap << 9) + (I0) + kg)) << 9) + ot * 16];

    #define LOADA(I0, DST)                                                      \
        _Pragma("unroll")                                                       \
        for (int tap = 0; tap < 3; ++tap)                                       \
            DST[tap] = hs[(rw + tap) * HPAD + (I0) + kg];

    #define DOMFMA(WF, AF)                                                      \
        _Pragma("unroll")                                                       \
        for (int tap = 0; tap < 3; ++tap) {                                     \
            double a = (double)AF[tap];                                         \
            _Pragma("unroll")                                                   \
            for (int ot = 0; ot < 4; ++ot)                                      \
                acc[ot] = __builtin_amdgcn_mfma_f64_16x16x4f64(                 \
                    a, (double)WF[tap * 4 + ot], acc[ot], 0, 0, 0);             \
        }

    float wfA[12], afA[3], wfB[12], afB[3];
    LOADW(0, wfA); LOADA(0, afA);
    for (int ic = 0; ic < 128; ic += 2) {
        const int i1 = (ic + 1) * 4;
        LOADW(i1, wfB); LOADA(i1, afB);     // prefetch odd step
        DOMFMA(wfA, afA);                    // compute even step
        if (ic + 2 < 128) {
            const int i2 = (ic + 2) * 4;
            LOADW(i2, wfA); LOADA(i2, afA); // prefetch next even step
        }
        DOMFMA(wfB, afB);                    // compute odd step
    }

    // ---- epilogue: p(t) = sum_o out_w[o]*relu(y+cb[o]) over this wave's 64 o ----
    double pl[4] = {0.0, 0.0, 0.0, 0.0};
    #pragma unroll
    for (int ot = 0; ot < 4; ++ot) {
        int o = w * 64 + ot * 16 + rw;
        double cbv = (double)cb[o];
        double owv = (double)ow[o];
        #pragma unroll
        for (int v = 0; v < 4; ++v) {
            double z = acc[ot][v] + cbv;
            z = z > 0.0 ? z : 0.0;
            pl[v] = fma(owv, z, pl[v]);
        }
    }
    #pragma unroll
    for (int v = 0; v < 4; ++v) {
        #pragma unroll
        for (int off = 1; off < 16; off <<= 1)
            pl[v] += __shfl_xor(pl[v], off);
    }
    if (rw == 0) {
        const int q = lane >> 4;           // row group: rows 4q+v
        #pragma unroll
        for (int v = 0; v < 4; ++v)
            part[((size_t)b * T_ + t0 + 4 * q + v) * 8 + w] = pl[v];
    }
    #undef LOADW
    #undef LOADA
    #undef DOMFMA
}

// ============ K2: per-batch alpha finish + wave prefix-scan + fire records ============
__global__ void k_scan(const double* __restrict__ part, const float* __restrict__ mask,
                       const float* __restrict__ outb,
                       float* __restrict__ out_tok, float* __restrict__ out_alpha,
                       double* __restrict__ a64, int* __restrict__ fire_t,
                       double* __restrict__ fire_frac, int* __restrict__ blen) {
    const int b = blockIdx.x;
    const int lane = threadIdx.x;
    const double ob = (double)outb[0];
    double carry = 0.0;
    int nf = 0;

    for (int c = 0; c < 65; ++c) {
        int t = c * 64 + lane;
        double a = 0.0;
        if (t < T_) {
            double o = ob;
            #pragma unroll
            for (int j = 0; j < 8; ++j)
                o += part[((size_t)b * T_ + t) * 8 + j];
            double s = 1.0 / (1.0 + exp(-o));
            double ap = s * SMOOTH_FACTOR - NOISE_THRESHOLD;
            if (ap < 0.0) ap = 0.0;
            double mk = (double)mask[b * T_ + t];
            double mprev = (t == 0) ? 1.0 : (double)mask[b * T_ + t - 1];
            a = ap * mk + TAIL_THRESHOLD * (mprev - mk);
        } else if (t == T_) {
            double mprev = (double)mask[b * T_ + T_ - 1];
            a = TAIL_THRESHOLD * mprev;
        }
        if (t <= T_) {
            out_alpha[(size_t)b * T1_ + t] = (float)a;
            a64[(size_t)b * T1_ + t] = a;
        }
        double x = a;
        #pragma unroll
        for (int off = 1; off < 64; off <<= 1) {
            double y = __shfl_up(x, off);
            if (lane >= off) x += y;
        }
        double ps = carry + x;
        double ps_prev = __shfl_up(ps, 1);
        if (lane == 0) ps_prev = carry;
        double psf = floor(ps), ppsf = floor(ps_prev);
        bool fire = (t <= T_) && (psf > ppsf);
        unsigned long long m = __ballot(fire);
        if (fire) {
            int k = nf + (int)__popcll(m & ((1ull << lane) - 1ull));
            fire_t[(size_t)b * T1_ + k] = t;
            fire_frac[(size_t)b * T1_ + k] = ps - psf;
        }
        nf += (int)__popcll(m);
        carry = __shfl(ps, 63);
    }
    if (lane == 0) {
        blen[b] = nf;
        out_tok[b] = (float)floor(carry);
    }
}

// ============ K3: frame construction (f64 accumulate) ============
__global__ void k_frames(const float* __restrict__ h, const double* __restrict__ a64,
                         const int* __restrict__ fire_t, const double* __restrict__ fire_frac,
                         const int* __restrict__ blen, float* __restrict__ out, int K) {
    const int k = blockIdx.x;
    const int b = blockIdx.y;
    const int tid = threadIdx.x;
    double ax = 0.0, ay = 0.0, az = 0.0, aw = 0.0;
    const int len = blen[b];
    if (k < len) {
        const int t1 = fire_t[(size_t)b * T1_ + k];
        const int t0 = (k > 0) ? fire_t[(size_t)b * T1_ + k - 1] : -1;
        const double f1 = fire_frac[(size_t)b * T1_ + k];
        const double f0 = (k > 0) ? fire_frac[(size_t)b * T1_ + k - 1] : 0.0;
        if (t0 >= 0 && t0 < T_) {
            float4 hv = *(const float4*)(h + ((size_t)b * T_ + t0) * D_ + (tid << 2));
            ax = fma(f0, (double)hv.x, ax); ay = fma(f0, (double)hv.y, ay);
            az = fma(f0, (double)hv.z, az); aw = fma(f0, (double)hv.w, aw);
        }
        for (int t = t0 + 1; t <= t1; ++t) {
            if (t >= T_) break;
            double c = a64[(size_t)b * T1_ + t] - ((t == t1) ? f1 : 0.0);
            float4 hv = *(const float4*)(h + ((size_t)b * T_ + t) * D_ + (tid << 2));
            ax = fma(c, (double)hv.x, ax); ay = fma(c, (double)hv.y, ay);
            az = fma(c, (double)hv.z, az); aw = fma(c, (double)hv.w, aw);
        }
    }
    float4 o = make_float4((float)ax, (float)ay, (float)az, (float)aw);
    *(float4*)(out + ((size_t)b * K + k) * D_ + (tid << 2)) = o;
}

// ============ host ============
extern "C" void kernel_launch(void* const* d_in, const int* in_sizes, int n_in,
                              void* d_out, int out_size, void* d_ws, size_t ws_size,
                              hipStream_t stream) {
    const float* h    = (const float*)d_in[0];
    const float* mask = (const float*)d_in[1];
    const float* cw   = (const float*)d_in[2];
    const float* cb   = (const float*)d_in[3];
    const float* ow   = (const float*)d_in[4];
    const float* ob   = (const float*)d_in[5];

    char* ws = (char*)d_ws;
    float*  wtf       = (float*)(ws + WTF_OFF);
    double* part      = (double*)(ws + PART_OFF);
    double* a64       = (double*)(ws + A64_OFF);
    int*    fire_t    = (int*)(ws + FT_OFF);
    double* fire_frac = (double*)(ws + FF_OFF);
    int*    blen      = (int*)(ws + LEN_OFF);

    long long K = ((long long)out_size - B_ - (long long)B_ * T1_) / ((long long)B_ * D_);
    if (K < 1) K = 1;
    float* out_ac    = (float*)d_out;
    float* out_tok   = out_ac + (size_t)B_ * K * D_;
    float* out_alpha = out_tok + B_;

    k_wt<<<dim3((3 * D_ * D_ + 255) / 256), dim3(256), 0, stream>>>(cw, wtf);
    k_conv<<<dim3(T_ / 16, B_), dim3(NTHR), 0, stream>>>(h, wtf, cb, ow, part);
    k_scan<<<dim3(B_), dim3(64), 0, stream>>>(part, mask, ob, out_tok, out_alpha,
                                              a64, fire_t, fire_frac, blen);
    k_frames<<<dim3((unsigned)K, B_), dim3(128), 0, stream>>>(h, a64, fire_t, fire_frac,
                                                              blen, out_ac, (int)K);
}

// Round 4
// 442.728 us; speedup vs baseline: 13.5286x; 3.8194x over previous
//
#include <hip/hip_runtime.h>
#include <math.h>

#define B_ 16
#define T_ 4096
#define D_ 512
#define T1_ 4097
#define NTHR 512

#define SMOOTH_FACTOR 1.0
#define NOISE_THRESHOLD 0.0
#define TAIL_THRESHOLD 0.45

typedef short bf16x8 __attribute__((ext_vector_type(8)));
typedef float f32x16 __attribute__((ext_vector_type(16)));
union U4 { uint4 u; bf16x8 s; };

// ---- workspace layout (bytes) ----
#define WB_OFF   ((size_t)0)         // bf16 W frags [comp][c][kg][o][e]: 2*96*2*512*8*2 = 3145728
#define PART_OFF ((size_t)3145728)   // f64 partial[b][t][8]: 4194304
#define A64_OFF  ((size_t)7340032)   // f64 alpha[b][T1]: 524416
#define FT_OFF   ((size_t)7864448)   // i32 fire_t[b][T1]: 262208
#define FF_OFF   ((size_t)8126656)   // f64 fire_frac[b][T1]: 524416
#define LEN_OFF  ((size_t)8651072)   // i32 batch_len[b]: 64

__device__ __forceinline__ unsigned bf_rne(unsigned x) {
    return (x + 0x7FFFu + ((x >> 16) & 1u)) >> 16;
}

// ============ K0: conv_w [o][i][k] f32 -> bf16 hi/mid fragment stream ============
// wb uint4 index = ((comp*96 + c)*2 + kg)*512 + o ; element e=0..7 packed;
// k = c*16 + kg*8 + e; tap = k>>9; i = k&511.
__global__ void k_wt(const float* __restrict__ cw, uint4* __restrict__ wb) {
    int idx = blockIdx.x * 256 + threadIdx.x;
    if (idx >= 196608) return;
    int o  = idx & 511;
    int r  = idx >> 9;
    int kg = r & 1;
    int rc = r >> 1;
    int comp = rc / 96;
    int c    = rc - comp * 96;
    unsigned uw[4];
    #pragma unroll
    for (int j = 0; j < 4; ++j) {
        unsigned short us[2];
        #pragma unroll
        for (int q = 0; q < 2; ++q) {
            int e = j * 2 + q;
            int k = c * 16 + kg * 8 + e;
            int tap = k >> 9, i = k & 511;
            float v = cw[((size_t)o * D_ + i) * 3 + tap];
            unsigned x  = __float_as_uint(v);
            unsigned hi = bf_rne(x);
            if (comp == 0) us[q] = (unsigned short)hi;
            else {
                float rem = v - __uint_as_float(hi << 16);
                us[q] = (unsigned short)bf_rne(__float_as_uint(rem));
            }
        }
        uw[j] = (unsigned)us[0] | ((unsigned)us[1] << 16);
    }
    wb[idx] = make_uint4(uw[0], uw[1], uw[2], uw[3]);
}

// ============ K1: bf16x2-split MFMA conv + fused relu-dot partials ============
// grid (T_/64, B_), 512 thr (8 waves). Wave w: o in [w*64, w*64+64), all 64 t.
// A tile (hi/mid bf16) in LDS [66 rows][65 uint4]; W frags from global (L2).
__global__ __launch_bounds__(NTHR)
void k_conv(const float* __restrict__ h, const uint4* __restrict__ wb,
            const float* __restrict__ cbp, const float* __restrict__ owp,
            double* __restrict__ part) {
    extern __shared__ uint4 lds[];
    uint4* Ahi = lds;              // [66][65] uint4
    uint4* Ami = lds + 66 * 65;

    const int tid  = threadIdx.x;
    const int b    = blockIdx.y;
    const int t0   = blockIdx.x * 64;
    const int lane = tid & 63;
    const int w    = tid >> 6;
    const int l31  = lane & 31;
    const int kg   = lane >> 5;

    // ---- stage h rows t0-1..t0+64, split f32 -> bf16 hi/mid ----
    const float* hb = h + (size_t)b * T_ * D_;
    for (int idx = tid; idx < 66 * 64; idx += NTHR) {
        int r = idx >> 6, cbk = idx & 63;
        int t = t0 - 1 + r;
        float v[8];
        if (t >= 0 && t < T_) {
            float4 x0 = *(const float4*)(hb + (size_t)t * D_ + cbk * 8);
            float4 x1 = *(const float4*)(hb + (size_t)t * D_ + cbk * 8 + 4);
            v[0]=x0.x; v[1]=x0.y; v[2]=x0.z; v[3]=x0.w;
            v[4]=x1.x; v[5]=x1.y; v[6]=x1.z; v[7]=x1.w;
        } else {
            #pragma unroll
            for (int j = 0; j < 8; ++j) v[j] = 0.f;
        }
        unsigned hw[4], mw[4];
        #pragma unroll
        for (int j = 0; j < 4; ++j) {
            unsigned short hs_[2], ms_[2];
            #pragma unroll
            for (int q = 0; q < 2; ++q) {
                float f = v[j * 2 + q];
                unsigned hi = bf_rne(__float_as_uint(f));
                float rem = f - __uint_as_float(hi << 16);
                hs_[q] = (unsigned short)hi;
                ms_[q] = (unsigned short)bf_rne(__float_as_uint(rem));
            }
            hw[j] = hs_[0] | ((unsigned)hs_[1] << 16);
            mw[j] = ms_[0] | ((unsigned)ms_[1] << 16);
        }
        Ahi[r * 65 + cbk] = make_uint4(hw[0], hw[1], hw[2], hw[3]);
        Ami[r * 65 + cbk] = make_uint4(mw[0], mw[1], mw[2], mw[3]);
    }
    __syncthreads();

    f32x16 acc00 = {0,0,0,0,0,0,0,0,0,0,0,0,0,0,0,0};
    f32x16 acc01 = acc00, acc10 = acc00, acc11 = acc00;

    // W fragment pointers: [comp][ot], chunk stride 1024 uint4 (16KB)
    const uint4* wp00 = wb + ((size_t)kg * 512 + w * 64 + l31);
    const uint4* wp01 = wp00 + 32;
    const uint4* wp10 = wp00 + 98304;
    const uint4* wp11 = wp01 + 98304;

    U4 a0hA,a0mA,a1hA,a1mA,w0hA,w1hA,w0mA,w1mA;
    U4 a0hB,a0mB,a1hB,a1mB,w0hB,w1hB,w0mB,w1mB;

    #define LOADC(c, a0h,a0m,a1h,a1m,w0h,w1h,w0m,w1m) {                 \
        int tap_ = (c) >> 5;                                            \
        int ia_  = (l31 + tap_) * 65 + (((c) & 31) << 1) + kg;          \
        a0h.u = Ahi[ia_];          a0m.u = Ami[ia_];                    \
        a1h.u = Ahi[ia_ + 32*65];  a1m.u = Ami[ia_ + 32*65];            \
        w0h.u = wp00[(size_t)(c) * 1024];                               \
        w1h.u = wp01[(size_t)(c) * 1024];                               \
        w0m.u = wp10[(size_t)(c) * 1024];                               \
        w1m.u = wp11[(size_t)(c) * 1024]; }

    #define MFMAC(a0h,a0m,a1h,a1m,w0h,w1h,w0m,w1m) {                                   \
        acc00 = __builtin_amdgcn_mfma_f32_32x32x16_bf16(a0h.s, w0h.s, acc00, 0,0,0);   \
        acc00 = __builtin_amdgcn_mfma_f32_32x32x16_bf16(a0h.s, w0m.s, acc00, 0,0,0);   \
        acc00 = __builtin_amdgcn_mfma_f32_32x32x16_bf16(a0m.s, w0h.s, acc00, 0,0,0);   \
        acc00 = __builtin_amdgcn_mfma_f32_32x32x16_bf16(a0m.s, w0m.s, acc00, 0,0,0);   \
        acc01 = __builtin_amdgcn_mfma_f32_32x32x16_bf16(a0h.s, w1h.s, acc01, 0,0,0);   \
        acc01 = __builtin_amdgcn_mfma_f32_32x32x16_bf16(a0h.s, w1m.s, acc01, 0,0,0);   \
        acc01 = __builtin_amdgcn_mfma_f32_32x32x16_bf16(a0m.s, w1h.s, acc01, 0,0,0);   \
        acc01 = __builtin_amdgcn_mfma_f32_32x32x16_bf16(a0m.s, w1m.s, acc01, 0,0,0);   \
        acc10 = __builtin_amdgcn_mfma_f32_32x32x16_bf16(a1h.s, w0h.s, acc10, 0,0,0);   \
        acc10 = __builtin_amdgcn_mfma_f32_32x32x16_bf16(a1h.s, w0m.s, acc10, 0,0,0);   \
        acc10 = __builtin_amdgcn_mfma_f32_32x32x16_bf16(a1m.s, w0h.s, acc10, 0,0,0);   \
        acc10 = __builtin_amdgcn_mfma_f32_32x32x16_bf16(a1m.s, w0m.s, acc10, 0,0,0);   \
        acc11 = __builtin_amdgcn_mfma_f32_32x32x16_bf16(a1h.s, w1h.s, acc11, 0,0,0);   \
        acc11 = __builtin_amdgcn_mfma_f32_32x32x16_bf16(a1h.s, w1m.s, acc11, 0,0,0);   \
        acc11 = __builtin_amdgcn_mfma_f32_32x32x16_bf16(a1m.s, w1h.s, acc11, 0,0,0);   \
        acc11 = __builtin_amdgcn_mfma_f32_32x32x16_bf16(a1m.s, w1m.s, acc11, 0,0,0); }

    LOADC(0, a0hA,a0mA,a1hA,a1mA,w0hA,w1hA,w0mA,w1mA);
    for (int c = 0; c < 96; c += 2) {
        LOADC(c + 1, a0hB,a0mB,a1hB,a1mB,w0hB,w1hB,w0mB,w1mB);
        MFMAC(a0hA,a0mA,a1hA,a1mA,w0hA,w1hA,w0mA,w1mA);
        if (c + 2 < 96)
            LOADC(c + 2, a0hA,a0mA,a1hA,a1mA,w0hA,w1hA,w0mA,w1mA);
        MFMAC(a0hB,a0mB,a1hB,a1mB,w0hB,w1hB,w0mB,w1mB);
    }
    #undef LOADC
    #undef MFMAC

    // ---- epilogue: f64 relu-dot over this wave's 64 o, half-wave reduce ----
    const int o0 = w * 64 + l31, o1 = o0 + 32;
    const double cb0 = (double)cbp[o0], cb1 = (double)cbp[o1];
    const double ow0 = (double)owp[o0], ow1 = (double)owp[o1];
    #pragma unroll
    for (int mt = 0; mt < 2; ++mt) {
        const f32x16 aco0 = mt ? acc10 : acc00;
        const f32x16 aco1 = mt ? acc11 : acc01;
        #pragma unroll
        for (int v = 0; v < 16; ++v) {
            double z0 = (double)aco0[v] + cb0; z0 = z0 > 0.0 ? z0 : 0.0;
            double z1 = (double)aco1[v] + cb1; z1 = z1 > 0.0 ? z1 : 0.0;
            double p = fma(ow0, z0, ow1 * z1);
            #pragma unroll
            for (int off = 1; off < 32; off <<= 1) p += __shfl_xor(p, off);
            if (l31 == 0) {
                int m = (v & 3) + 8 * (v >> 2) + 4 * kg;
                part[((size_t)b * T_ + t0 + mt * 32 + m) * 8 + w] = p;
            }
        }
    }
}

// ============ K2: per-batch alpha finish + wave prefix-scan + fire records ============
__global__ void k_scan(const double* __restrict__ part, const float* __restrict__ mask,
                       const float* __restrict__ outb,
                       float* __restrict__ out_tok, float* __restrict__ out_alpha,
                       double* __restrict__ a64, int* __restrict__ fire_t,
                       double* __restrict__ fire_frac, int* __restrict__ blen) {
    const int b = blockIdx.x;
    const int lane = threadIdx.x;
    const double ob = (double)outb[0];
    double carry = 0.0;
    int nf = 0;

    for (int c = 0; c < 65; ++c) {
        int t = c * 64 + lane;
        double a = 0.0;
        if (t < T_) {
            double o = ob;
            #pragma unroll
            for (int j = 0; j < 8; ++j)
                o += part[((size_t)b * T_ + t) * 8 + j];
            double s = 1.0 / (1.0 + exp(-o));
            double ap = s * SMOOTH_FACTOR - NOISE_THRESHOLD;
            if (ap < 0.0) ap = 0.0;
            double mk = (double)mask[b * T_ + t];
            double mprev = (t == 0) ? 1.0 : (double)mask[b * T_ + t - 1];
            a = ap * mk + TAIL_THRESHOLD * (mprev - mk);
        } else if (t == T_) {
            double mprev = (double)mask[b * T_ + T_ - 1];
            a = TAIL_THRESHOLD * mprev;
        }
        if (t <= T_) {
            out_alpha[(size_t)b * T1_ + t] = (float)a;
            a64[(size_t)b * T1_ + t] = a;
        }
        double x = a;
        #pragma unroll
        for (int off = 1; off < 64; off <<= 1) {
            double y = __shfl_up(x, off);
            if (lane >= off) x += y;
        }
        double ps = carry + x;
        double ps_prev = __shfl_up(ps, 1);
        if (lane == 0) ps_prev = carry;
        double psf = floor(ps), ppsf = floor(ps_prev);
        bool fire = (t <= T_) && (psf > ppsf);
        unsigned long long m = __ballot(fire);
        if (fire) {
            int k = nf + (int)__popcll(m & ((1ull << lane) - 1ull));
            fire_t[(size_t)b * T1_ + k] = t;
            fire_frac[(size_t)b * T1_ + k] = ps - psf;
        }
        nf += (int)__popcll(m);
        carry = __shfl(ps, 63);
    }
    if (lane == 0) {
        blen[b] = nf;
        out_tok[b] = (float)floor(carry);
    }
}

// ============ K3: frame construction (f64 accumulate) ============
__global__ void k_frames(const float* __restrict__ h, const double* __restrict__ a64,
                         const int* __restrict__ fire_t, const double* __restrict__ fire_frac,
                         const int* __restrict__ blen, float* __restrict__ out, int K) {
    const int k = blockIdx.x;
    const int b = blockIdx.y;
    const int tid = threadIdx.x;
    double ax = 0.0, ay = 0.0, az = 0.0, aw = 0.0;
    const int len = blen[b];
    if (k < len) {
        const int t1 = fire_t[(size_t)b * T1_ + k];
        const int t0 = (k > 0) ? fire_t[(size_t)b * T1_ + k - 1] : -1;
        const double f1 = fire_frac[(size_t)b * T1_ + k];
        const double f0 = (k > 0) ? fire_frac[(size_t)b * T1_ + k - 1] : 0.0;
        if (t0 >= 0 && t0 < T_) {
            float4 hv = *(const float4*)(h + ((size_t)b * T_ + t0) * D_ + (tid << 2));
            ax = fma(f0, (double)hv.x, ax); ay = fma(f0, (double)hv.y, ay);
            az = fma(f0, (double)hv.z, az); aw = fma(f0, (double)hv.w, aw);
        }
        for (int t = t0 + 1; t <= t1; ++t) {
            if (t >= T_) break;
            double c = a64[(size_t)b * T1_ + t] - ((t == t1) ? f1 : 0.0);
            float4 hv = *(const float4*)(h + ((size_t)b * T_ + t) * D_ + (tid << 2));
            ax = fma(c, (double)hv.x, ax); ay = fma(c, (double)hv.y, ay);
            az = fma(c, (double)hv.z, az); aw = fma(c, (double)hv.w, aw);
        }
    }
    float4 o = make_float4((float)ax, (float)ay, (float)az, (float)aw);
    *(float4*)(out + ((size_t)b * K + k) * D_ + (tid << 2)) = o;
}

// ============ host ============
extern "C" void kernel_launch(void* const* d_in, const int* in_sizes, int n_in,
                              void* d_out, int out_size, void* d_ws, size_t ws_size,
                              hipStream_t stream) {
    const float* h    = (const float*)d_in[0];
    const float* mask = (const float*)d_in[1];
    const float* cw   = (const float*)d_in[2];
    const float* cb   = (const float*)d_in[3];
    const float* ow   = (const float*)d_in[4];
    const float* ob   = (const float*)d_in[5];

    char* ws = (char*)d_ws;
    uint4*  wb        = (uint4*)(ws + WB_OFF);
    double* part      = (double*)(ws + PART_OFF);
    double* a64       = (double*)(ws + A64_OFF);
    int*    fire_t    = (int*)(ws + FT_OFF);
    double* fire_frac = (double*)(ws + FF_OFF);
    int*    blen      = (int*)(ws + LEN_OFF);

    long long K = ((long long)out_size - B_ - (long long)B_ * T1_) / ((long long)B_ * D_);
    if (K < 1) K = 1;
    float* out_ac    = (float*)d_out;
    float* out_tok   = out_ac + (size_t)B_ * K * D_;
    float* out_alpha = out_tok + B_;

    const int lds = 2 * 66 * 65 * 16;   // 137280 B
    (void)hipFuncSetAttribute((const void*)k_conv,
                              hipFuncAttributeMaxDynamicSharedMemorySize, lds);

    k_wt<<<dim3(768), dim3(256), 0, stream>>>(cw, wb);
    k_conv<<<dim3(T_ / 64, B_), dim3(NTHR), lds, stream>>>(h, wb, cb, ow, part);
    k_scan<<<dim3(B_), dim3(64), 0, stream>>>(part, mask, ob, out_tok, out_alpha,
                                              a64, fire_t, fire_frac, blen);
    k_frames<<<dim3((unsigned)K, B_), dim3(128), 0, stream>>>(h, a64, fire_t, fire_frac,
                                                              blen, out_ac, (int)K);
}